// Round 7
// baseline (467.354 us; speedup 1.0000x reference)
//
#include <hip/hip_runtime.h>
#include <hip/hip_bf16.h>
#include <cstdint>
#include <cstddef>

// Problem constants
#define B_  2
#define S_  4096
#define D_  512
#define H_  8
#define HD_ 64
#define QSCALE_ 0.18033688f   // 0.125 * log2(e): scores come out in exp2 domain

typedef short s16x8 __attribute__((ext_vector_type(8)));
typedef float f32x4 __attribute__((ext_vector_type(4)));

__device__ __forceinline__ unsigned short f2bf(float f) {
    unsigned u = __builtin_bit_cast(unsigned, f);
    u += 0x7fffu + ((u >> 16) & 1u);   // round-to-nearest-even (finite values only)
    return (unsigned short)(u >> 16);
}

__device__ __forceinline__ unsigned packbf2(float a, float b) {
    unsigned r;
    asm("v_cvt_pk_bf16_f32 %0, %1, %2" : "=v"(r) : "v"(a), "v"(b));
    return r;
}

// async global->LDS, 16B per lane; dst must be wave-uniform base (lane*16 added by HW)
__device__ __forceinline__ void gload16(const unsigned short* g, unsigned short* l) {
    __builtin_amdgcn_global_load_lds(
        (const __attribute__((address_space(1))) void*)g,
        (__attribute__((address_space(3))) void*)l,
        16, 0, 0);
}

// K tile: 128 rows x 128B, swizzle ((row&7)<<4)
__device__ __forceinline__ s16x8 kfr(const unsigned short* buf, int kr, int hb) {
    return *(const s16x8*)((const char*)buf + kr * 128 + (hb ^ ((kr & 7) << 4)));
}
// V tile: 64 rows x 256B, swizzle ((row&15)<<4)
__device__ __forceinline__ s16x8 vfr_(const unsigned short* buf, int vr, int kbyte) {
    return *(const s16x8*)((const char*)buf + vr * 256 + (kbyte ^ ((vr & 15) << 4)));
}

// ---------------------------------------------------------------------------
// Kernel 1: cast + transpose the four weight matrices to bf16, wt[n][k]
// ---------------------------------------------------------------------------
__global__ __launch_bounds__(256)
void prep_weights(const float* __restrict__ wq, const float* __restrict__ wk,
                  const float* __restrict__ wv, const float* __restrict__ wo,
                  unsigned short* __restrict__ wt) {
    int e = blockIdx.x * 256 + threadIdx.x;      // 4 * 512 * 512 total
    int mat = e >> 18;
    int i = e & 262143;
    int n = i >> 9, k = i & 511;
    const float* w = (mat == 0) ? wq : (mat == 1) ? wk : (mat == 2) ? wv : wo;
    wt[(size_t)mat * 262144 + n * 512 + k] = f2bf(w[k * 512 + n]);
}

// ---------------------------------------------------------------------------
// Kernel 2a: fused Q/K/V projection GEMM (blockIdx.z selects matrix).
//   z=0: Q (scale QSCALE_, [t][c] bf16)   z=1: K ([t][c] bf16)
//   z=2: V (head-transposed [b][h][hd][s] bf16, LDS-staged transposed store)
// ---------------------------------------------------------------------------
__global__ __launch_bounds__(256)
void qkv_gemm(const float* __restrict__ qx, const float* __restrict__ kx,
              const float* __restrict__ vx, const unsigned short* __restrict__ wtb,
              const float* __restrict__ bqp, const float* __restrict__ bkp,
              const float* __restrict__ bvp,
              unsigned short* __restrict__ qo, unsigned short* __restrict__ ko,
              unsigned short* __restrict__ vo) {
    __shared__ unsigned short xs[64 * 72];
    __shared__ unsigned short wsd[64 * 72];

    const int z = blockIdx.z;
    const float* xin = (z == 0) ? qx : (z == 1) ? kx : vx;
    const unsigned short* wt = wtb + (size_t)z * 262144;
    const float* bias = (z == 0) ? bqp : (z == 1) ? bkp : bvp;
    const float oscale = (z == 0) ? QSCALE_ : 1.0f;

    const int tid  = threadIdx.x;
    const int wave = tid >> 6, lane = tid & 63;
    const int l15 = lane & 15, l4 = lane >> 4;
    const int row0 = blockIdx.x * 64, col0 = blockIdx.y * 64;
    const int sr = tid >> 2, seg = tid & 3;

    f32x4 acc[4] = {};

    for (int kt = 0; kt < 512; kt += 64) {
        {
            const float* x = xin + (size_t)(row0 + sr) * 512 + kt + seg * 16;
            unsigned short tmp[16];
            #pragma unroll
            for (int j = 0; j < 16; j += 4) {
                float4 v = *(const float4*)(x + j);
                tmp[j] = f2bf(v.x); tmp[j+1] = f2bf(v.y); tmp[j+2] = f2bf(v.z); tmp[j+3] = f2bf(v.w);
            }
            *(s16x8*)&xs[sr * 72 + seg * 16]     = *(s16x8*)&tmp[0];
            *(s16x8*)&xs[sr * 72 + seg * 16 + 8] = *(s16x8*)&tmp[8];
        }
        {
            const unsigned short* wp = wt + (size_t)(col0 + sr) * 512 + kt + seg * 16;
            *(s16x8*)&wsd[sr * 72 + seg * 16]     = *(const s16x8*)(wp);
            *(s16x8*)&wsd[sr * 72 + seg * 16 + 8] = *(const s16x8*)(wp + 8);
        }
        __syncthreads();

        #pragma unroll
        for (int ks = 0; ks < 2; ++ks) {
            s16x8 a = *(const s16x8*)&xs[(wave * 16 + l15) * 72 + ks * 32 + l4 * 8];
            #pragma unroll
            for (int ng = 0; ng < 4; ++ng) {
                s16x8 b = *(const s16x8*)&wsd[(ng * 16 + l15) * 72 + ks * 32 + l4 * 8];
                acc[ng] = __builtin_amdgcn_mfma_f32_16x16x32_bf16(a, b, acc[ng], 0, 0, 0);
            }
        }
        __syncthreads();
    }

    if (z == 2) {
        // stage transposed tile in LDS, then contiguous stores along s
        #pragma unroll
        for (int ng = 0; ng < 4; ++ng) {
            float bv = bias[col0 + ng * 16 + l15];
            #pragma unroll
            for (int r = 0; r < 4; ++r)
                xs[(ng * 16 + l15) * 72 + wave * 16 + l4 * 4 + r] = f2bf(acc[ng][r] + bv);
        }
        __syncthreads();
        const int bb = row0 >> 12, s0l = row0 & 4095, hh = col0 >> 6;
        unsigned short* dst = vo + ((size_t)(bb * H_ + hh) * HD_ + sr) * S_ + s0l + seg * 16;
        *(s16x8*)dst       = *(const s16x8*)&xs[sr * 72 + seg * 16];
        *(s16x8*)(dst + 8) = *(const s16x8*)&xs[sr * 72 + seg * 16 + 8];
    } else {
        unsigned short* out = (z == 0) ? qo : ko;
        #pragma unroll
        for (int ng = 0; ng < 4; ++ng) {
            int c = col0 + ng * 16 + l15;
            float bv = bias[c];
            #pragma unroll
            for (int r = 0; r < 4; ++r) {
                int t = row0 + wave * 16 + l4 * 4 + r;
                out[(size_t)t * 512 + c] = f2bf((acc[ng][r] + bv) * oscale);
            }
        }
    }
}

// ---------------------------------------------------------------------------
// Kernel 2b: output projection GEMM (bf16 in, fp32 out)
// ---------------------------------------------------------------------------
__global__ __launch_bounds__(256)
void oproj_gemm(const unsigned short* __restrict__ xin, const unsigned short* __restrict__ wt,
                const float* __restrict__ bias, float* __restrict__ out) {
    __shared__ unsigned short xs[64 * 72];
    __shared__ unsigned short wsd[64 * 72];

    const int tid  = threadIdx.x;
    const int wave = tid >> 6, lane = tid & 63;
    const int l15 = lane & 15, l4 = lane >> 4;
    const int row0 = blockIdx.x * 64, col0 = blockIdx.y * 64;
    const int sr = tid >> 2, seg = tid & 3;

    f32x4 acc[4] = {};

    for (int kt = 0; kt < 512; kt += 64) {
        {
            const unsigned short* x = xin + (size_t)(row0 + sr) * 512 + kt + seg * 16;
            *(s16x8*)&xs[sr * 72 + seg * 16]     = *(const s16x8*)(x);
            *(s16x8*)&xs[sr * 72 + seg * 16 + 8] = *(const s16x8*)(x + 8);
        }
        {
            const unsigned short* wp = wt + (size_t)(col0 + sr) * 512 + kt + seg * 16;
            *(s16x8*)&wsd[sr * 72 + seg * 16]     = *(const s16x8*)(wp);
            *(s16x8*)&wsd[sr * 72 + seg * 16 + 8] = *(const s16x8*)(wp + 8);
        }
        __syncthreads();

        #pragma unroll
        for (int ks = 0; ks < 2; ++ks) {
            s16x8 a = *(const s16x8*)&xs[(wave * 16 + l15) * 72 + ks * 32 + l4 * 8];
            #pragma unroll
            for (int ng = 0; ng < 4; ++ng) {
                s16x8 b = *(const s16x8*)&wsd[(ng * 16 + l15) * 72 + ks * 32 + l4 * 8];
                acc[ng] = __builtin_amdgcn_mfma_f32_16x16x32_bf16(a, b, acc[ng], 0, 0, 0);
            }
        }
        __syncthreads();
    }

    #pragma unroll
    for (int ng = 0; ng < 4; ++ng) {
        int c = col0 + ng * 16 + l15;
        float bv = bias[c];
        #pragma unroll
        for (int r = 0; r < 4; ++r) {
            int t = row0 + wave * 16 + l4 * 4 + r;
            out[(size_t)t * 512 + c] = acc[ng][r] + bv;
        }
    }
}

// ---------------------------------------------------------------------------
// Kernel 3: fused attention (R4-proven two-pass). 256 threads (4 waves),
// 128 q/block, 32 q/wave. KVBLK=128 double-buffered chunks.
// Pass 1: per-lane exp2 denom. Pass 2: normalized P, NT weight stores, PV.
// ---------------------------------------------------------------------------
__global__ __launch_bounds__(256)
void attn_kernel(const unsigned short* __restrict__ qb,
                 const unsigned short* __restrict__ kb,
                 const unsigned short* __restrict__ vt,
                 float* __restrict__ wout,          // weights tensor base [B,H,S,S]
                 unsigned short* __restrict__ ob) { // pre-projection output, bf16 [t][512]
    __shared__ unsigned short kbuf[2][8192];   // 128 keys x 64 hd (128B rows, swizzled)
    __shared__ unsigned short vbuf[2][8192];   // 64 hd x 128 keys (256B rows, swizzled)
    __shared__ unsigned short pstrip[4][2048]; // per-wave 32q x 64k bf16 (swizzled)

    const int tid  = threadIdx.x;
    const int wave = tid >> 6, lane = tid & 63;
    const int l15 = lane & 15, l4 = lane >> 4;

    // XCD-aware swizzle (512 blocks, bijective)
    const int lid = blockIdx.x;
    const int wid = (lid & 7) * 64 + (lid >> 3);
    const int bh = wid >> 5;
    const int q0 = (wid & 31) * 128;
    const int b = bh >> 3, h = bh & 7;

    const int ksrow = lane >> 3;
    const int kscol = 8 * ((lane & 7) ^ ksrow);
    const unsigned short* kstg0 = kb + (size_t)(b * S_ + wave * 32 + ksrow) * 512 + h * 64 + kscol;
    const int vsrow = lane >> 4;

#define KSTAGE(c, bsel)                                                         \
    { _Pragma("unroll")                                                         \
      for (int i_ = 0; i_ < 4; ++i_)                                            \
          gload16(kstg0 + ((size_t)(c) * 128 + i_ * 8) * 512,                   \
                  &kbuf[bsel][(wave * 32 + i_ * 8) * 64]); }

#define VSTAGE(c, bsel)                                                         \
    { _Pragma("unroll")                                                         \
      for (int i_ = 0; i_ < 4; ++i_) {                                          \
          int vrow_ = wave * 16 + i_ * 4 + vsrow;                               \
          int vcb_  = (lane & 15) ^ (i_ * 4 + vsrow);                           \
          gload16(vt + ((size_t)(bh * 64) + vrow_) * 4096 + (c) * 128 + vcb_ * 8, \
                  &vbuf[bsel][(wave * 16 + i_ * 4) * 128]); } }

    // Q fragments: 2 q-halves x 2 k-halves (pre-scaled by 0.125*log2e)
    s16x8 aq[2][2];
    #pragma unroll
    for (int qh = 0; qh < 2; ++qh) {
        const int t = b * S_ + q0 + wave * 32 + qh * 16 + l15;
        const unsigned short* qp = qb + (size_t)t * 512 + h * 64;
        aq[qh][0] = *(const s16x8*)(qp + l4 * 8);
        aq[qh][1] = *(const s16x8*)(qp + 32 + l4 * 8);
    }

    // ---------------- pass 1: per-lane denominators ----------------
    float lsum[2] = {0.0f, 0.0f};
    KSTAGE(0, 0);
    __syncthreads();

    for (int c = 0; c < 32; ++c) {
        const int cur = c & 1;
        if (c < 31) KSTAGE(c + 1, cur ^ 1);

        #pragma unroll
        for (int sub = 0; sub < 2; ++sub) {
            f32x4 sc[4][2] = {};
            #pragma unroll
            for (int ks = 0; ks < 2; ++ks)
                #pragma unroll
                for (int kg = 0; kg < 4; ++kg) {
                    s16x8 kf = kfr(kbuf[cur], sub * 64 + kg * 16 + l15, ks * 64 + l4 * 16);
                    sc[kg][0] = __builtin_amdgcn_mfma_f32_16x16x32_bf16(kf, aq[0][ks], sc[kg][0], 0, 0, 0);
                    sc[kg][1] = __builtin_amdgcn_mfma_f32_16x16x32_bf16(kf, aq[1][ks], sc[kg][1], 0, 0, 0);
                }
            #pragma unroll
            for (int kg = 0; kg < 4; ++kg)
                #pragma unroll
                for (int r = 0; r < 4; ++r) {
                    lsum[0] += __builtin_amdgcn_exp2f(sc[kg][0][r]);
                    lsum[1] += __builtin_amdgcn_exp2f(sc[kg][1][r]);
                }
        }
        __syncthreads();
    }

    #pragma unroll
    for (int qh = 0; qh < 2; ++qh) {
        lsum[qh] += __shfl_xor(lsum[qh], 16);
        lsum[qh] += __shfl_xor(lsum[qh], 32);
    }
    const float off[2] = { -__builtin_amdgcn_logf(lsum[0]),
                           -__builtin_amdgcn_logf(lsum[1]) };

    // ---------------- pass 2: weights out + O accumulation ----------------
    f32x4 ao[2][4] = {};
    float* wbase = wout + ((size_t)bh * S_ + q0 + wave * 32) * S_;
    unsigned short* strip = &pstrip[wave][0];

    KSTAGE(0, 0); VSTAGE(0, 0);
    __syncthreads();

    for (int c = 0; c < 32; ++c) {
        const int cur = c & 1;
        if (c < 31) { KSTAGE(c + 1, cur ^ 1); VSTAGE(c + 1, cur ^ 1); }

        #pragma unroll
        for (int sub = 0; sub < 2; ++sub) {
            f32x4 sc[4][2] = {};
            #pragma unroll
            for (int ks = 0; ks < 2; ++ks)
                #pragma unroll
                for (int kg = 0; kg < 4; ++kg) {
                    s16x8 kf = kfr(kbuf[cur], sub * 64 + kg * 16 + l15, ks * 64 + l4 * 16);
                    sc[kg][0] = __builtin_amdgcn_mfma_f32_16x16x32_bf16(kf, aq[0][ks], sc[kg][0], 0, 0, 0);
                    sc[kg][1] = __builtin_amdgcn_mfma_f32_16x16x32_bf16(kf, aq[1][ks], sc[kg][1], 0, 0, 0);
                }

            // normalized weights: NT f32x4 stores + packed bf16 strip
            #pragma unroll
            for (int qh = 0; qh < 2; ++qh) {
                float* wrow = wbase + (size_t)(qh * 16 + l15) * S_ + c * 128 + sub * 64;
                const int q = qh * 16 + l15;
                #pragma unroll
                for (int kg = 0; kg < 4; ++kg) {
                    f32x4 w;
                    #pragma unroll
                    for (int r = 0; r < 4; ++r)
                        w[r] = __builtin_amdgcn_exp2f(sc[kg][qh][r] + off[qh]);
                    __builtin_nontemporal_store(w, (f32x4*)(wrow + kg * 16 + l4 * 4));
                    uint2 pk;
                    pk.x = packbf2(w[0], w[1]);
                    pk.y = packbf2(w[2], w[3]);
                    *(uint2*)((char*)strip + q * 128 + ((kg * 32 + l4 * 8) ^ ((q & 7) << 4))) = pk;
                }
            }

            // PV: A = P strip frags (wave-private), B = V frags (reused 2x)
            #pragma unroll
            for (int ks = 0; ks < 2; ++ks) {
                s16x8 pa0 = *(const s16x8*)((const char*)strip + l15 * 128
                               + ((ks * 64 + l4 * 16) ^ ((l15 & 7) << 4)));
                s16x8 pa1 = *(const s16x8*)((const char*)strip + (16 + l15) * 128
                               + ((ks * 64 + l4 * 16) ^ ((l15 & 7) << 4)));
                #pragma unroll
                for (int ng = 0; ng < 4; ++ng) {
                    s16x8 vf = vfr_(vbuf[cur], ng * 16 + l15, sub * 128 + ks * 64 + l4 * 16);
                    ao[0][ng] = __builtin_amdgcn_mfma_f32_16x16x32_bf16(pa0, vf, ao[0][ng], 0, 0, 0);
                    ao[1][ng] = __builtin_amdgcn_mfma_f32_16x16x32_bf16(pa1, vf, ao[1][ng], 0, 0, 0);
                }
            }
        }
        __syncthreads();
    }

    // store O tile (pre-projection) as bf16 [t][512]
    #pragma unroll
    for (int qg = 0; qg < 2; ++qg)
        #pragma unroll
        for (int ng = 0; ng < 4; ++ng) {
            int hd = ng * 16 + l15;
            #pragma unroll
            for (int r = 0; r < 4; ++r) {
                int t = b * S_ + q0 + wave * 32 + qg * 16 + l4 * 4 + r;
                ob[(size_t)t * 512 + h * 64 + hd] = f2bf(ao[qg][ng][r]);
            }
        }
#undef KSTAGE
#undef VSTAGE
}

// ---------------------------------------------------------------------------
// Launch
// ---------------------------------------------------------------------------
extern "C" void kernel_launch(void* const* d_in, const int* in_sizes, int n_in,
                              void* d_out, int out_size, void* d_ws, size_t ws_size,
                              hipStream_t stream) {
    (void)in_sizes; (void)n_in; (void)out_size; (void)ws_size;

    const float* query = (const float*)d_in[0];
    const float* key_  = (const float*)d_in[1];
    const float* value = (const float*)d_in[2];
    const float* wq = (const float*)d_in[3];
    const float* bq = (const float*)d_in[4];
    const float* wk = (const float*)d_in[5];
    const float* bk = (const float*)d_in[6];
    const float* wv = (const float*)d_in[7];
    const float* bv = (const float*)d_in[8];
    const float* wo = (const float*)d_in[9];
    const float* bo = (const float*)d_in[10];
    float* out = (float*)d_out;

    // workspace: wt 2MB | qb 8MB | kb 8MB | vt 8MB | ob 8MB
    char* ws = (char*)d_ws;
    unsigned short* wt = (unsigned short*)(ws);
    unsigned short* qb = (unsigned short*)(ws + 2097152);
    unsigned short* kb = (unsigned short*)(ws + 2097152 + 1 * 8388608);
    unsigned short* vt = (unsigned short*)(ws + 2097152 + 2 * 8388608);
    unsigned short* ob = (unsigned short*)(ws + 2097152 + 3 * 8388608);

    hipLaunchKernelGGL(prep_weights, dim3(4096), dim3(256), 0, stream, wq, wk, wv, wo, wt);

    hipLaunchKernelGGL(qkv_gemm, dim3(128, 8, 3), dim3(256), 0, stream,
                       query, key_, value, wt, bq, bk, bv, qb, kb, vt);

    hipLaunchKernelGGL(attn_kernel, dim3(512), dim3(256), 0, stream,
                       qb, kb, vt, out + 4194304, ob);

    hipLaunchKernelGGL(oproj_gemm, dim3(128, 8), dim3(256), 0, stream,
                       ob, wt + 3 * 262144, bo, out);
}

// Round 8
// 367.798 us; speedup vs baseline: 1.2707x; 1.2707x over previous
//
#include <hip/hip_runtime.h>
#include <hip/hip_bf16.h>
#include <cstdint>
#include <cstddef>

// Problem constants
#define B_  2
#define S_  4096
#define D_  512
#define H_  8
#define HD_ 64
#define QSCALE_ 0.18033688f   // 0.125 * log2(e): scores come out in exp2 domain

typedef short s16x8 __attribute__((ext_vector_type(8)));
typedef float f32x4 __attribute__((ext_vector_type(4)));

__device__ __forceinline__ unsigned short f2bf(float f) {
    unsigned u = __builtin_bit_cast(unsigned, f);
    u += 0x7fffu + ((u >> 16) & 1u);   // round-to-nearest-even (finite values only)
    return (unsigned short)(u >> 16);
}

__device__ __forceinline__ unsigned packbf2(float a, float b) {
    unsigned r;
    asm("v_cvt_pk_bf16_f32 %0, %1, %2" : "=v"(r) : "v"(a), "v"(b));
    return r;
}

// async global->LDS, 16B per lane; dst must be wave-uniform base (lane*16 added by HW)
__device__ __forceinline__ void gload16(const unsigned short* g, unsigned short* l) {
    __builtin_amdgcn_global_load_lds(
        (const __attribute__((address_space(1))) void*)g,
        (__attribute__((address_space(3))) void*)l,
        16, 0, 0);
}

// K tile: 128 rows x 128B, swizzle ((row&7)<<4)
__device__ __forceinline__ s16x8 kfr(const unsigned short* buf, int kr, int hb) {
    return *(const s16x8*)((const char*)buf + kr * 128 + (hb ^ ((kr & 7) << 4)));
}
// V tile: 64 rows x 256B, swizzle ((row&15)<<4)
__device__ __forceinline__ s16x8 vfr_(const unsigned short* buf, int vr, int kbyte) {
    return *(const s16x8*)((const char*)buf + vr * 256 + (kbyte ^ ((vr & 15) << 4)));
}

// ---------------------------------------------------------------------------
// Kernel 1: cast + transpose the four weight matrices to bf16, wt[n][k]
// ---------------------------------------------------------------------------
__global__ __launch_bounds__(256)
void prep_weights(const float* __restrict__ wq, const float* __restrict__ wk,
                  const float* __restrict__ wv, const float* __restrict__ wo,
                  unsigned short* __restrict__ wt) {
    int e = blockIdx.x * 256 + threadIdx.x;      // 4 * 512 * 512 total
    int mat = e >> 18;
    int i = e & 262143;
    int n = i >> 9, k = i & 511;
    const float* w = (mat == 0) ? wq : (mat == 1) ? wk : (mat == 2) ? wv : wo;
    wt[(size_t)mat * 262144 + n * 512 + k] = f2bf(w[k * 512 + n]);
}

// ---------------------------------------------------------------------------
// Kernel 2a: fused Q/K/V projection GEMM (blockIdx.z selects matrix).
//   z=0: Q (scale QSCALE_, [t][c] bf16)   z=1: K ([t][c] bf16)
//   z=2: V (head-transposed [b][h][hd][s] bf16, LDS-staged transposed store)
// ---------------------------------------------------------------------------
__global__ __launch_bounds__(256)
void qkv_gemm(const float* __restrict__ qx, const float* __restrict__ kx,
              const float* __restrict__ vx, const unsigned short* __restrict__ wtb,
              const float* __restrict__ bqp, const float* __restrict__ bkp,
              const float* __restrict__ bvp,
              unsigned short* __restrict__ qo, unsigned short* __restrict__ ko,
              unsigned short* __restrict__ vo) {
    __shared__ unsigned short xs[64 * 72];
    __shared__ unsigned short wsd[64 * 72];

    const int z = blockIdx.z;
    const float* xin = (z == 0) ? qx : (z == 1) ? kx : vx;
    const unsigned short* wt = wtb + (size_t)z * 262144;
    const float* bias = (z == 0) ? bqp : (z == 1) ? bkp : bvp;
    const float oscale = (z == 0) ? QSCALE_ : 1.0f;

    const int tid  = threadIdx.x;
    const int wave = tid >> 6, lane = tid & 63;
    const int l15 = lane & 15, l4 = lane >> 4;
    const int row0 = blockIdx.x * 64, col0 = blockIdx.y * 64;
    const int sr = tid >> 2, seg = tid & 3;

    f32x4 acc[4] = {};

    for (int kt = 0; kt < 512; kt += 64) {
        {
            const float* x = xin + (size_t)(row0 + sr) * 512 + kt + seg * 16;
            unsigned short tmp[16];
            #pragma unroll
            for (int j = 0; j < 16; j += 4) {
                float4 v = *(const float4*)(x + j);
                tmp[j] = f2bf(v.x); tmp[j+1] = f2bf(v.y); tmp[j+2] = f2bf(v.z); tmp[j+3] = f2bf(v.w);
            }
            *(s16x8*)&xs[sr * 72 + seg * 16]     = *(s16x8*)&tmp[0];
            *(s16x8*)&xs[sr * 72 + seg * 16 + 8] = *(s16x8*)&tmp[8];
        }
        {
            const unsigned short* wp = wt + (size_t)(col0 + sr) * 512 + kt + seg * 16;
            *(s16x8*)&wsd[sr * 72 + seg * 16]     = *(const s16x8*)(wp);
            *(s16x8*)&wsd[sr * 72 + seg * 16 + 8] = *(const s16x8*)(wp + 8);
        }
        __syncthreads();

        #pragma unroll
        for (int ks = 0; ks < 2; ++ks) {
            s16x8 a = *(const s16x8*)&xs[(wave * 16 + l15) * 72 + ks * 32 + l4 * 8];
            #pragma unroll
            for (int ng = 0; ng < 4; ++ng) {
                s16x8 b = *(const s16x8*)&wsd[(ng * 16 + l15) * 72 + ks * 32 + l4 * 8];
                acc[ng] = __builtin_amdgcn_mfma_f32_16x16x32_bf16(a, b, acc[ng], 0, 0, 0);
            }
        }
        __syncthreads();
    }

    if (z == 2) {
        // stage transposed tile in LDS, then contiguous stores along s
        #pragma unroll
        for (int ng = 0; ng < 4; ++ng) {
            float bv = bias[col0 + ng * 16 + l15];
            #pragma unroll
            for (int r = 0; r < 4; ++r)
                xs[(ng * 16 + l15) * 72 + wave * 16 + l4 * 4 + r] = f2bf(acc[ng][r] + bv);
        }
        __syncthreads();
        const int bb = row0 >> 12, s0l = row0 & 4095, hh = col0 >> 6;
        unsigned short* dst = vo + ((size_t)(bb * H_ + hh) * HD_ + sr) * S_ + s0l + seg * 16;
        *(s16x8*)dst       = *(const s16x8*)&xs[sr * 72 + seg * 16];
        *(s16x8*)(dst + 8) = *(const s16x8*)&xs[sr * 72 + seg * 16 + 8];
    } else {
        unsigned short* out = (z == 0) ? qo : ko;
        #pragma unroll
        for (int ng = 0; ng < 4; ++ng) {
            int c = col0 + ng * 16 + l15;
            float bv = bias[c];
            #pragma unroll
            for (int r = 0; r < 4; ++r) {
                int t = row0 + wave * 16 + l4 * 4 + r;
                out[(size_t)t * 512 + c] = f2bf((acc[ng][r] + bv) * oscale);
            }
        }
    }
}

// ---------------------------------------------------------------------------
// Kernel 2b: output projection GEMM (bf16 in, fp32 out)
// ---------------------------------------------------------------------------
__global__ __launch_bounds__(256)
void oproj_gemm(const unsigned short* __restrict__ xin, const unsigned short* __restrict__ wt,
                const float* __restrict__ bias, float* __restrict__ out) {
    __shared__ unsigned short xs[64 * 72];
    __shared__ unsigned short wsd[64 * 72];

    const int tid  = threadIdx.x;
    const int wave = tid >> 6, lane = tid & 63;
    const int l15 = lane & 15, l4 = lane >> 4;
    const int row0 = blockIdx.x * 64, col0 = blockIdx.y * 64;
    const int sr = tid >> 2, seg = tid & 3;

    f32x4 acc[4] = {};

    for (int kt = 0; kt < 512; kt += 64) {
        {
            const unsigned short* x = xin + (size_t)(row0 + sr) * 512 + kt + seg * 16;
            *(s16x8*)&xs[sr * 72 + seg * 16]     = *(const s16x8*)(x);
            *(s16x8*)&xs[sr * 72 + seg * 16 + 8] = *(const s16x8*)(x + 8);
        }
        {
            const unsigned short* wp = wt + (size_t)(col0 + sr) * 512 + kt + seg * 16;
            *(s16x8*)&wsd[sr * 72 + seg * 16]     = *(const s16x8*)(wp);
            *(s16x8*)&wsd[sr * 72 + seg * 16 + 8] = *(const s16x8*)(wp + 8);
        }
        __syncthreads();

        #pragma unroll
        for (int ks = 0; ks < 2; ++ks) {
            s16x8 a = *(const s16x8*)&xs[(wave * 16 + l15) * 72 + ks * 32 + l4 * 8];
            #pragma unroll
            for (int ng = 0; ng < 4; ++ng) {
                s16x8 b = *(const s16x8*)&wsd[(ng * 16 + l15) * 72 + ks * 32 + l4 * 8];
                acc[ng] = __builtin_amdgcn_mfma_f32_16x16x32_bf16(a, b, acc[ng], 0, 0, 0);
            }
        }
        __syncthreads();
    }

    #pragma unroll
    for (int ng = 0; ng < 4; ++ng) {
        int c = col0 + ng * 16 + l15;
        float bv = bias[c];
        #pragma unroll
        for (int r = 0; r < 4; ++r) {
            int t = row0 + wave * 16 + l4 * 4 + r;
            out[(size_t)t * 512 + c] = acc[ng][r] + bv;
        }
    }
}

// ---------------------------------------------------------------------------
// Kernel 3: fused attention (R4-proven two-pass). 256 threads (4 waves),
// 128 q/block, 32 q/wave. KVBLK=128 double-buffered chunks.
// Pass 1: per-lane exp2 denom. Pass 2: normalized P, plain f32x4 weight
// stores (nt REVERTED: regressed 49us in R7), PV. s_setprio around MFMA.
// ---------------------------------------------------------------------------
__global__ __launch_bounds__(256)
void attn_kernel(const unsigned short* __restrict__ qb,
                 const unsigned short* __restrict__ kb,
                 const unsigned short* __restrict__ vt,
                 float* __restrict__ wout,          // weights tensor base [B,H,S,S]
                 unsigned short* __restrict__ ob) { // pre-projection output, bf16 [t][512]
    __shared__ unsigned short kbuf[2][8192];   // 128 keys x 64 hd (128B rows, swizzled)
    __shared__ unsigned short vbuf[2][8192];   // 64 hd x 128 keys (256B rows, swizzled)
    __shared__ unsigned short pstrip[4][2048]; // per-wave 32q x 64k bf16 (swizzled)

    const int tid  = threadIdx.x;
    const int wave = tid >> 6, lane = tid & 63;
    const int l15 = lane & 15, l4 = lane >> 4;

    // XCD-aware swizzle (512 blocks, bijective)
    const int lid = blockIdx.x;
    const int wid = (lid & 7) * 64 + (lid >> 3);
    const int bh = wid >> 5;
    const int q0 = (wid & 31) * 128;
    const int b = bh >> 3, h = bh & 7;

    const int ksrow = lane >> 3;
    const int kscol = 8 * ((lane & 7) ^ ksrow);
    const unsigned short* kstg0 = kb + (size_t)(b * S_ + wave * 32 + ksrow) * 512 + h * 64 + kscol;
    const int vsrow = lane >> 4;

#define KSTAGE(c, bsel)                                                         \
    { _Pragma("unroll")                                                         \
      for (int i_ = 0; i_ < 4; ++i_)                                            \
          gload16(kstg0 + ((size_t)(c) * 128 + i_ * 8) * 512,                   \
                  &kbuf[bsel][(wave * 32 + i_ * 8) * 64]); }

#define VSTAGE(c, bsel)                                                         \
    { _Pragma("unroll")                                                         \
      for (int i_ = 0; i_ < 4; ++i_) {                                          \
          int vrow_ = wave * 16 + i_ * 4 + vsrow;                               \
          int vcb_  = (lane & 15) ^ (i_ * 4 + vsrow);                           \
          gload16(vt + ((size_t)(bh * 64) + vrow_) * 4096 + (c) * 128 + vcb_ * 8, \
                  &vbuf[bsel][(wave * 16 + i_ * 4) * 128]); } }

    // Q fragments: 2 q-halves x 2 k-halves (pre-scaled by 0.125*log2e)
    s16x8 aq[2][2];
    #pragma unroll
    for (int qh = 0; qh < 2; ++qh) {
        const int t = b * S_ + q0 + wave * 32 + qh * 16 + l15;
        const unsigned short* qp = qb + (size_t)t * 512 + h * 64;
        aq[qh][0] = *(const s16x8*)(qp + l4 * 8);
        aq[qh][1] = *(const s16x8*)(qp + 32 + l4 * 8);
    }

    // ---------------- pass 1: per-lane denominators ----------------
    float lsum[2] = {0.0f, 0.0f};
    KSTAGE(0, 0);
    __syncthreads();

    for (int c = 0; c < 32; ++c) {
        const int cur = c & 1;
        if (c < 31) KSTAGE(c + 1, cur ^ 1);

        #pragma unroll
        for (int sub = 0; sub < 2; ++sub) {
            f32x4 sc[4][2] = {};
            __builtin_amdgcn_s_setprio(1);
            #pragma unroll
            for (int ks = 0; ks < 2; ++ks)
                #pragma unroll
                for (int kg = 0; kg < 4; ++kg) {
                    s16x8 kf = kfr(kbuf[cur], sub * 64 + kg * 16 + l15, ks * 64 + l4 * 16);
                    sc[kg][0] = __builtin_amdgcn_mfma_f32_16x16x32_bf16(kf, aq[0][ks], sc[kg][0], 0, 0, 0);
                    sc[kg][1] = __builtin_amdgcn_mfma_f32_16x16x32_bf16(kf, aq[1][ks], sc[kg][1], 0, 0, 0);
                }
            __builtin_amdgcn_s_setprio(0);
            #pragma unroll
            for (int kg = 0; kg < 4; ++kg)
                #pragma unroll
                for (int r = 0; r < 4; ++r) {
                    lsum[0] += __builtin_amdgcn_exp2f(sc[kg][0][r]);
                    lsum[1] += __builtin_amdgcn_exp2f(sc[kg][1][r]);
                }
        }
        __syncthreads();
    }

    #pragma unroll
    for (int qh = 0; qh < 2; ++qh) {
        lsum[qh] += __shfl_xor(lsum[qh], 16);
        lsum[qh] += __shfl_xor(lsum[qh], 32);
    }
    const float off[2] = { -__builtin_amdgcn_logf(lsum[0]),
                           -__builtin_amdgcn_logf(lsum[1]) };

    // ---------------- pass 2: weights out + O accumulation ----------------
    f32x4 ao[2][4] = {};
    float* wbase = wout + ((size_t)bh * S_ + q0 + wave * 32) * S_;
    unsigned short* strip = &pstrip[wave][0];

    KSTAGE(0, 0); VSTAGE(0, 0);
    __syncthreads();

    for (int c = 0; c < 32; ++c) {
        const int cur = c & 1;
        if (c < 31) { KSTAGE(c + 1, cur ^ 1); VSTAGE(c + 1, cur ^ 1); }

        #pragma unroll
        for (int sub = 0; sub < 2; ++sub) {
            f32x4 sc[4][2] = {};
            __builtin_amdgcn_s_setprio(1);
            #pragma unroll
            for (int ks = 0; ks < 2; ++ks)
                #pragma unroll
                for (int kg = 0; kg < 4; ++kg) {
                    s16x8 kf = kfr(kbuf[cur], sub * 64 + kg * 16 + l15, ks * 64 + l4 * 16);
                    sc[kg][0] = __builtin_amdgcn_mfma_f32_16x16x32_bf16(kf, aq[0][ks], sc[kg][0], 0, 0, 0);
                    sc[kg][1] = __builtin_amdgcn_mfma_f32_16x16x32_bf16(kf, aq[1][ks], sc[kg][1], 0, 0, 0);
                }
            __builtin_amdgcn_s_setprio(0);

            // normalized weights: plain f32x4 stores + packed bf16 strip
            #pragma unroll
            for (int qh = 0; qh < 2; ++qh) {
                float* wrow = wbase + (size_t)(qh * 16 + l15) * S_ + c * 128 + sub * 64;
                const int q = qh * 16 + l15;
                #pragma unroll
                for (int kg = 0; kg < 4; ++kg) {
                    f32x4 w;
                    #pragma unroll
                    for (int r = 0; r < 4; ++r)
                        w[r] = __builtin_amdgcn_exp2f(sc[kg][qh][r] + off[qh]);
                    *(f32x4*)(wrow + kg * 16 + l4 * 4) = w;
                    uint2 pk;
                    pk.x = packbf2(w[0], w[1]);
                    pk.y = packbf2(w[2], w[3]);
                    *(uint2*)((char*)strip + q * 128 + ((kg * 32 + l4 * 8) ^ ((q & 7) << 4))) = pk;
                }
            }

            // PV: A = P strip frags (wave-private), B = V frags (reused 2x)
            __builtin_amdgcn_s_setprio(1);
            #pragma unroll
            for (int ks = 0; ks < 2; ++ks) {
                s16x8 pa0 = *(const s16x8*)((const char*)strip + l15 * 128
                               + ((ks * 64 + l4 * 16) ^ ((l15 & 7) << 4)));
                s16x8 pa1 = *(const s16x8*)((const char*)strip + (16 + l15) * 128
                               + ((ks * 64 + l4 * 16) ^ ((l15 & 7) << 4)));
                #pragma unroll
                for (int ng = 0; ng < 4; ++ng) {
                    s16x8 vf = vfr_(vbuf[cur], ng * 16 + l15, sub * 128 + ks * 64 + l4 * 16);
                    ao[0][ng] = __builtin_amdgcn_mfma_f32_16x16x32_bf16(pa0, vf, ao[0][ng], 0, 0, 0);
                    ao[1][ng] = __builtin_amdgcn_mfma_f32_16x16x32_bf16(pa1, vf, ao[1][ng], 0, 0, 0);
                }
            }
            __builtin_amdgcn_s_setprio(0);
        }
        __syncthreads();
    }

    // store O tile (pre-projection) as bf16 [t][512]
    #pragma unroll
    for (int qg = 0; qg < 2; ++qg)
        #pragma unroll
        for (int ng = 0; ng < 4; ++ng) {
            int hd = ng * 16 + l15;
            #pragma unroll
            for (int r = 0; r < 4; ++r) {
                int t = b * S_ + q0 + wave * 32 + qg * 16 + l4 * 4 + r;
                ob[(size_t)t * 512 + h * 64 + hd] = f2bf(ao[qg][ng][r]);
            }
        }
#undef KSTAGE
#undef VSTAGE
}

// ---------------------------------------------------------------------------
// Launch
// ---------------------------------------------------------------------------
extern "C" void kernel_launch(void* const* d_in, const int* in_sizes, int n_in,
                              void* d_out, int out_size, void* d_ws, size_t ws_size,
                              hipStream_t stream) {
    (void)in_sizes; (void)n_in; (void)out_size; (void)ws_size;

    const float* query = (const float*)d_in[0];
    const float* key_  = (const float*)d_in[1];
    const float* value = (const float*)d_in[2];
    const float* wq = (const float*)d_in[3];
    const float* bq = (const float*)d_in[4];
    const float* wk = (const float*)d_in[5];
    const float* bk = (const float*)d_in[6];
    const float* wv = (const float*)d_in[7];
    const float* bv = (const float*)d_in[8];
    const float* wo = (const float*)d_in[9];
    const float* bo = (const float*)d_in[10];
    float* out = (float*)d_out;

    // workspace: wt 2MB | qb 8MB | kb 8MB | vt 8MB | ob 8MB
    char* ws = (char*)d_ws;
    unsigned short* wt = (unsigned short*)(ws);
    unsigned short* qb = (unsigned short*)(ws + 2097152);
    unsigned short* kb = (unsigned short*)(ws + 2097152 + 1 * 8388608);
    unsigned short* vt = (unsigned short*)(ws + 2097152 + 2 * 8388608);
    unsigned short* ob = (unsigned short*)(ws + 2097152 + 3 * 8388608);

    hipLaunchKernelGGL(prep_weights, dim3(4096), dim3(256), 0, stream, wq, wk, wv, wo, wt);

    hipLaunchKernelGGL(qkv_gemm, dim3(128, 8, 3), dim3(256), 0, stream,
                       query, key_, value, wt, bq, bk, bv, qb, kb, vt);

    hipLaunchKernelGGL(attn_kernel, dim3(512), dim3(256), 0, stream,
                       qb, kb, vt, out + 4194304, ob);

    hipLaunchKernelGGL(oproj_gemm, dim3(128, 8), dim3(256), 0, stream,
                       ob, wt + 3 * 262144, bo, out);
}